// Round 1
// baseline (62.115 us; speedup 1.0000x reference)
//
#include <hip/hip_runtime.h>

// Problem constants: x[64][16][8192] f32, J=4, LEVELS=13, BN eps 1e-5.
// masked_targets[j] = blockmean with block 2^(13-j)
// masked_inputs[j]  = j==0 ? blockmean(8192) : blockmean(2^(13-j)) - blockmean(2^(14-j))
// Output [2][4][64][16][8192] f32.

#define NROWS 1024          // 64*16
#define ROWLEN 8192
#define STATS_STRIDE 16     // 15 floats padded to 16
// stats layout per row: [0]=m0, [1..2]=m1, [3..6]=m2, [7..14]=m3

__global__ __launch_bounds__(256) void row_stats_kernel(const float* __restrict__ x,
                                                        float* __restrict__ stats) {
    int row = blockIdx.x;                 // 0..1023
    const float4* xr = reinterpret_cast<const float4*>(x) + (size_t)row * (ROWLEN / 4);
    int t = threadIdx.x;                  // 0..255
    float s[8];
#pragma unroll
    for (int k = 0; k < 8; ++k) {
        float4 v = xr[t + 256 * k];       // iteration k covers 1024-block k
        s[k] = (v.x + v.y) + (v.z + v.w);
    }
    __shared__ float red[8][4];
    __shared__ float m3s[8];
    int lane = t & 63, wave = t >> 6;
#pragma unroll
    for (int k = 0; k < 8; ++k) {
        float v = s[k];
#pragma unroll
        for (int off = 32; off; off >>= 1) v += __shfl_down(v, off, 64);
        if (lane == 0) red[k][wave] = v;
    }
    __syncthreads();
    if (t < 8) m3s[t] = (red[t][0] + red[t][1] + red[t][2] + red[t][3]) * (1.0f / 1024.0f);
    __syncthreads();
    if (t == 0) {
        float* o = stats + (size_t)row * STATS_STRIDE;
        float m2[4], m1[2];
#pragma unroll
        for (int k = 0; k < 4; ++k) m2[k] = 0.5f * (m3s[2 * k] + m3s[2 * k + 1]);
        m1[0] = 0.5f * (m2[0] + m2[1]);
        m1[1] = 0.5f * (m2[2] + m2[3]);
        float m0 = 0.5f * (m1[0] + m1[1]);
        o[0] = m0;
        o[1] = m1[0]; o[2] = m1[1];
        o[3] = m2[0]; o[4] = m2[1]; o[5] = m2[2]; o[6] = m2[3];
#pragma unroll
        for (int k = 0; k < 8; ++k) o[7 + k] = m3s[k];
    }
}

// One block per (j,c); 64 threads = one wave, thread b handles batch b.
__global__ __launch_bounds__(64) void bn_stats_kernel(const float* __restrict__ stats,
                                                      const float* __restrict__ gamma,
                                                      const float* __restrict__ beta,
                                                      float* __restrict__ bn /*[4][16][2]*/) {
    int j = blockIdx.x >> 4;
    int c = blockIdx.x & 15;
    int b = threadIdx.x;                  // 0..63
    const float* s = stats + (size_t)((b << 4) + c) * STATS_STRIDE;
    float sum = 0.f, sum2 = 0.f;
    float B = (float)(ROWLEN >> j);       // samples per block at level j
    if (j == 0) {
        float d = s[0];
        sum = d; sum2 = d * d;
    } else {
        int base = (1 << j) - 1;
        int pbase = (1 << (j - 1)) - 1;
        int nb = 1 << j;
        for (int k = 0; k < nb; ++k) {
            float d = s[base + k] - s[pbase + (k >> 1)];
            sum += d; sum2 += d * d;
        }
    }
    sum *= B; sum2 *= B;
#pragma unroll
    for (int off = 32; off; off >>= 1) {
        sum  += __shfl_down(sum, off, 64);
        sum2 += __shfl_down(sum2, off, 64);
    }
    if (b == 0) {
        const float N = 64.0f * 8192.0f;
        float mean = sum / N;
        float var = sum2 / N - mean * mean;
        float inv = rsqrtf(var + 1e-5f);
        float scale = gamma[(j << 4) + c] * inv;
        float shift = beta[(j << 4) + c] - mean * scale;
        bn[((j << 4) + c) * 2 + 0] = scale;
        bn[((j << 4) + c) * 2 + 1] = shift;
    }
}

// Streaming writer: 2*4*64*16*8192 = 2^26 floats = 2^24 float4.
__global__ __launch_bounds__(256) void write_out_kernel(const float* __restrict__ stats,
                                                        const float* __restrict__ bn,
                                                        float4* __restrict__ out) {
    unsigned idx = blockIdx.x * blockDim.x + threadIdx.x;
    unsigned stride = gridDim.x * blockDim.x;
    const unsigned total = 1u << 24;
    for (unsigned i = idx; i < total; i += stride) {
        unsigned e = i << 2;                     // element index
        unsigned n = e & 8191u;
        unsigned c = (e >> 13) & 15u;
        unsigned b = (e >> 17) & 63u;
        unsigned j = (e >> 23) & 3u;
        unsigned part = (e >> 25) & 1u;
        const float* s = stats + (size_t)((b << 4) + c) * STATS_STRIDE;
        float mj = s[(1u << j) - 1u + (n >> (13u - j))];
        float val;
        if (part) {
            val = mj;                            // target: block mean
        } else {
            float d = mj;
            if (j > 0) d -= s[(1u << (j - 1u)) - 1u + (n >> (14u - j))];
            unsigned jc = (j << 4) + c;
            val = d * bn[jc * 2] + bn[jc * 2 + 1];
        }
        out[i] = make_float4(val, val, val, val);
    }
}

extern "C" void kernel_launch(void* const* d_in, const int* in_sizes, int n_in,
                              void* d_out, int out_size, void* d_ws, size_t ws_size,
                              hipStream_t stream) {
    const float* x     = (const float*)d_in[0];
    const float* gamma = (const float*)d_in[1];
    const float* beta  = (const float*)d_in[2];
    float* out = (float*)d_out;

    float* stats = (float*)d_ws;                           // 1024*16 floats = 64 KiB
    float* bn    = stats + (size_t)NROWS * STATS_STRIDE;   // 128 floats

    row_stats_kernel<<<NROWS, 256, 0, stream>>>(x, stats);
    bn_stats_kernel<<<64, 64, 0, stream>>>(stats, gamma, beta, bn);
    write_out_kernel<<<2048, 256, 0, stream>>>(stats, bn, (float4*)out);
}